// Round 18
// baseline (292.787 us; speedup 1.0000x reference)
//
#include <hip/hip_runtime.h>
#include <math.h>

#define N_USERS 50000
#define N_ITEMS 100000
#define N_ENT   200000
#define N_NODES (N_USERS + N_ITEMS)
#define N_REL   32
#define DIM     64

#define NB_KG  391          // (legacy constant: bcur sizing only)
#define NB_UI  586          // UI buckets: row>>8 (256 keys each)
#define NB_TOT (NB_KG + NB_UI)   // 977
#define CAPU   1536         // fixed capacity per UI bucket (max kept ~850)
#define CAPE   48           // fixed KG edge slots per entity (Poisson(10); P(>48)~1e-15)
#define NMMTILE 1563        // ceil(200000/128) matmul tiles
#define NSCAT  768          // scatter blocks (prefix — measured best, R8)
#define FUSE_GRID (NSCAT + NMMTILE)
#define NCPY   208          // user bf16-copy blocks (fused into kgagg dispatch)
#define KGOFF  (NB_UI + NCPY)    // 794: kgagg role offset in fused dispatch

__device__ __forceinline__ unsigned short f2bf(float f) {   // RNE f32->bf16
    unsigned u = __float_as_uint(f);
    u += 0x7FFFu + ((u >> 16) & 1u);
    return (unsigned short)(u >> 16);
}
__device__ __forceinline__ float bf_lo(unsigned v) { return __uint_as_float(v << 16); }
__device__ __forceinline__ float bf_hi(unsigned v) { return __uint_as_float(v & 0xFFFF0000u); }
__device__ __forceinline__ int getbit(const unsigned* m, int i) {
    return (m[i >> 5] >> (i & 31)) & 1;
}

// ---------------------------------------------------------------------------
// build_masks: membership bitmaps + bcur init + ecnt zero + gate table +
// INTENT table (block 0).
// ---------------------------------------------------------------------------
__global__ __launch_bounds__(256) void build_masks(const int* __restrict__ i2e,
                                                   const int* __restrict__ u,
                                                   const int* __restrict__ ipos,
                                                   const int* __restrict__ ineg,
                                                   const float* __restrict__ rel_emb,
                                                   const float* __restrict__ iw,
                                                   float2* __restrict__ gateg,
                                                   float* __restrict__ intentg,
                                                   unsigned* __restrict__ ent_mask,
                                                   unsigned* __restrict__ node_mask,
                                                   int* __restrict__ bcur,
                                                   int* __restrict__ ecnt,
                                                   int B) {
    int t = blockIdx.x * 256 + threadIdx.x;
    int stride = gridDim.x * 256;
    for (int i = threadIdx.x; i < NB_TOT; i += 256)          // same-value benign race
        bcur[i] = (i < NB_KG) ? 0 : (i - NB_KG) * CAPU;
    for (int i = t; i < N_ENT; i += stride) ecnt[i] = 0;
    if (blockIdx.x == 0) {
        for (int idx = threadIdx.x; idx < N_REL * 32; idx += 256) {
            int rel = idx >> 5, hl2 = idx & 31;
            float g0 = 1.0f / (1.0f + __expf(-rel_emb[rel * 64 + 2 * hl2]));
            float g1 = 1.0f / (1.0f + __expf(-rel_emb[rel * 64 + 2 * hl2 + 1]));
            gateg[idx] = make_float2(g0, g1);
        }
        if (threadIdx.x < 64) {
            int j = threadIdx.x;
            for (int k = 0; k < 2; k++) {
                float m = -1e30f;
                for (int r = 0; r < N_REL; r++) m = fmaxf(m, iw[k * N_REL + r]);
                float Z = 0.f, acc = 0.f;
                for (int r = 0; r < N_REL; r++) {
                    float e = __expf(iw[k * N_REL + r] - m);
                    Z += e;
                    acc += e * rel_emb[r * 64 + j];
                }
                intentg[k * 64 + j] = acc / Z;
            }
        }
    }
    for (int i = t; i < N_ITEMS; i += stride) {
        int e = i2e[i];
        atomicOr(&ent_mask[e >> 5], 1u << (e & 31));
    }
    for (int i = t; i < 3 * B; i += stride) {
        int r = (i < B) ? u[i]
              : (i < 2 * B) ? N_USERS + ipos[i - B]
                            : N_USERS + ineg[i - 2 * B];
        atomicOr(&node_mask[r >> 5], 1u << (r & 31));
    }
}

// ---------------------------------------------------------------------------
// mm_scatter: FUSED dispatch, TWO roles, PREFIX mapping (measured best):
//   blocks [0, NSCAT): edge scatter.
//     KG edges (R17): DIRECT per-entity scatter — pos=atomicAdd(&ecnt[d],1),
//       kgslot[d*48+pos]=src|rel<<18. 790K atomics over 200K counters =
//       ~25K cache lines (~32/line) — 3 orders below R13's contention
//       regime (950K over 61 lines). No sort needed: kgagg reads
//       ecnt/kgslot directly, finalize_kg dispatch DELETED.
//     UI edges: 3-phase LDS-hist (586-entry) into fixed-capacity buckets.
//   blocks [NSCAT, ...): ent_matmul tiles (swizzled 48KB LDS).
// Matmul FMA order k-ascending per output -> BIT-IDENTICAL numerics.
// ---------------------------------------------------------------------------
__global__ __launch_bounds__(512) void mm_scatter(const float* __restrict__ x,
                                                  const float* __restrict__ w,
                                                  unsigned short* __restrict__ y16,
                                                  int n_ent,
                                                  const int* __restrict__ kg_src,
                                                  const int* __restrict__ kg_dst,
                                                  const int* __restrict__ kg_rel,
                                                  const int* __restrict__ ui_row,
                                                  const int* __restrict__ ui_col,
                                                  const float* __restrict__ ui_vals,
                                                  const unsigned* __restrict__ ent_mask,
                                                  const unsigned* __restrict__ node_mask,
                                                  unsigned* __restrict__ colneed,
                                                  int* __restrict__ bcur,
                                                  int* __restrict__ ecnt,
                                                  unsigned int* __restrict__ kgslot,
                                                  int* __restrict__ uirec,
                                                  float* __restrict__ uval,
                                                  int e_kg, int e_ui) {
    __shared__ __align__(16) char smem[49152];
    int tid = threadIdx.x;
    int bid = blockIdx.x;

    if (bid < NSCAT) {
        // ---------------- scatter branch ----------------
        int* h     = (int*)smem;          // NB_UI counters
        int* lbase = h + NB_UI;
        int n = e_kg + e_ui;
        int nchunks = (n + 4095) >> 12;
        for (int c = bid; c < nchunks; c += NSCAT) {
            int base = c << 12;
            for (int i = tid; i < NB_UI; i += 512) h[i] = 0;
            __syncthreads();
            unsigned int rec[8];
            float val[8];
            int bk[8];
            #pragma unroll
            for (int j = 0; j < 8; j++) {
                int e = base + j * 512 + tid;
                bk[j] = -1;
                if (e < n) {
                    if (e < e_kg) {
                        int d = kg_dst[e];
                        if (getbit(ent_mask, d)) {   // KG: direct per-entity
                            unsigned r2 = (unsigned int)kg_src[e]
                                          | ((unsigned int)kg_rel[e] << 18);
                            int pos = atomicAdd(&ecnt[d], 1);
                            if (pos < CAPE) kgslot[(long)d * CAPE + pos] = r2;
                        }
                    } else {
                        int i2 = e - e_kg;
                        int r  = ui_row[i2];
                        if (getbit(node_mask, r)) {
                            int cc = ui_col[i2];
                            bk[j]  = r >> 8;
                            rec[j] = (unsigned int)cc
                                     | ((unsigned int)(r & 255) << 18);
                            val[j] = ui_vals[i2];
                            atomicAdd(&h[bk[j]], 1);
                            if (r < N_USERS) {        // user row -> item col needed
                                int ci = cc - N_USERS;
                                atomicOr(&colneed[ci >> 5], 1u << (ci & 31));
                            }
                        }
                    }
                }
            }
            __syncthreads();
            for (int i = tid; i < NB_UI; i += 512) {
                int cc = h[i];
                lbase[i] = cc ? atomicAdd(&bcur[NB_KG + i], cc) : 0;
            }
            __syncthreads();
            #pragma unroll
            for (int j = 0; j < 8; j++) {
                if (bk[j] >= 0) {
                    int pos = atomicAdd(&lbase[bk[j]], 1);
                    if (pos < (bk[j] + 1) * CAPU) { uirec[pos] = (int)rec[j]; uval[pos] = val[j]; }
                }
            }
            __syncthreads();
        }
        return;
    }

    // ---------------- matmul branch ----------------
    int mtile = bid - NSCAT;
    float (*xt)[128] = (float (*)[128])smem;            // 32768 B
    float (*wt)[64]  = (float (*)[64])(smem + 32768);   // 16384 B
    int base = mtile * 128;

    #pragma unroll
    for (int q = 0; q < 2; q++) {
        int idx = q * 512 + tid;          // 1024 float4 of w
        int j = idx >> 4, k4 = idx & 15;
        int s0 = (k4 << 2) & 28;          // sigma for rows 4k4..4k4+3
        float4 v = ((const float4*)w)[idx];
        wt[4 * k4 + 0][j ^ s0] = v.x;
        wt[4 * k4 + 1][j ^ s0] = v.y;
        wt[4 * k4 + 2][j ^ s0] = v.z;
        wt[4 * k4 + 3][j ^ s0] = v.w;
    }
    #pragma unroll
    for (int q = 0; q < 4; q++) {
        int idx = q * 512 + tid;          // 2048 float4 of x
        int r = idx >> 4, k4 = idx & 15;
        int gr = base + r;
        int s0 = (k4 << 2) & 28;
        if (gr < n_ent) {
            float4 v = ((const float4*)x)[(long)gr * 16 + k4];
            xt[4 * k4 + 0][r ^ s0] = v.x;
            xt[4 * k4 + 1][r ^ s0] = v.y;
            xt[4 * k4 + 2][r ^ s0] = v.z;
            xt[4 * k4 + 3][r ^ s0] = v.w;
        }
    }
    __syncthreads();

    int j0 = (tid & 7) * 8;               // 8 output cols
    int r0 = (tid >> 3) * 2;              // 2 output rows (0..126)
    float acc[2][8];
    #pragma unroll
    for (int i = 0; i < 2; i++)
        #pragma unroll
        for (int j = 0; j < 8; j++) acc[i][j] = 0.f;

    #pragma unroll 4
    for (int k = 0; k < 64; k++) {
        int s = k & 28;
        float2 xa = *(const float2*)&xt[k][r0 ^ s];
        float4 wa = *(const float4*)&wt[k][j0 ^ s];
        float4 wb = *(const float4*)&wt[k][(j0 + 4) ^ s];
        float xr[2] = {xa.x, xa.y};
        float wr[8] = {wa.x, wa.y, wa.z, wa.w, wb.x, wb.y, wb.z, wb.w};
        #pragma unroll
        for (int i = 0; i < 2; i++)
            #pragma unroll
            for (int j = 0; j < 8; j++)
                acc[i][j] += xr[i] * wr[j];
    }

    #pragma unroll
    for (int i = 0; i < 2; i++) {
        int gr = base + r0 + i;
        if (gr < n_ent) {
            uint4 o;
            o.x = (unsigned)f2bf(acc[i][0]) | ((unsigned)f2bf(acc[i][1]) << 16);
            o.y = (unsigned)f2bf(acc[i][2]) | ((unsigned)f2bf(acc[i][3]) << 16);
            o.z = (unsigned)f2bf(acc[i][4]) | ((unsigned)f2bf(acc[i][5]) << 16);
            o.w = (unsigned)f2bf(acc[i][6]) | ((unsigned)f2bf(acc[i][7]) << 16);
            *(uint4*)&y16[(long)gr * 64 + j0] = o;
        }
    }
}

// ---------------------------------------------------------------------------
// kgagg_fused: THREE roles — finalize_UI [0,586) | user-copy [586,794) |
// kgagg items [794,...) (half-wave, 2 items/wave, measured best).
// kgagg reads DIRECT per-entity slots (ecnt/kgslot) — no sort, no CSR;
// only depends on mm_scatter now. colneed skip (R16) retained.
// ---------------------------------------------------------------------------
__global__ __launch_bounds__(256) void kgagg_fused(const int* __restrict__ bcur,
                                                   int* __restrict__ uirec,
                                                   float* __restrict__ uval,
                                                   int* __restrict__ beg_ui,
                                                   int* __restrict__ end_ui,
                                                   const float* __restrict__ user_emb,
                                                   const int* __restrict__ ecnt,
                                                   const unsigned int* __restrict__ kgslot,
                                                   const unsigned short* __restrict__ y16,
                                                   const float* __restrict__ entity_emb,
                                                   const int* __restrict__ i2e,
                                                   const float4* __restrict__ gate4,
                                                   const unsigned* __restrict__ node_mask,
                                                   const unsigned* __restrict__ colneed,
                                                   float* __restrict__ all_emb,
                                                   unsigned short* __restrict__ all16) {
    __shared__ __align__(16) char smem[14336];   // rec_ui[1536] + fval[1536] + hist[512]
    int tid = threadIdx.x;
    int bid = blockIdx.x;

    if (bid < NB_UI) {
        // ---------------- finalize UI bucket ----------------
        unsigned int* rec = (unsigned int*)smem;            // 6144 B
        float* fval = (float*)(smem + 6144);                // 6144 B
        int*   hist = (int*)(smem + 12288);                 // 2048 B
        int b    = bid;
        int base = b * CAPU;
        int ne   = min(bcur[NB_KG + b] - base, CAPU);
        int key_base = b << 8;
        int nkeys = min(256, N_NODES - key_base);

        for (int i = tid; i < ne; i += 256) {
            rec[i] = (unsigned int)uirec[base + i];
            fval[i] = uval[base + i];
        }
        for (int i = tid; i < 512; i += 256) hist[i] = 0;
        __syncthreads();
        for (int i = tid; i < ne; i += 256)
            atomicAdd(&hist[rec[i] >> 18], 1);
        __syncthreads();
        int i0 = tid, i1 = tid + 256;
        int v0 = hist[i0], v1 = hist[i1];
        __syncthreads();
        for (int o = 1; o < 512; o <<= 1) {
            int a0 = (i0 >= o) ? hist[i0 - o] : 0;
            int a1 = (i1 >= o) ? hist[i1 - o] : 0;
            __syncthreads();
            hist[i0] += a0; hist[i1] += a1;
            __syncthreads();
        }
        int e0 = hist[i0] - v0, e1 = hist[i1] - v1;
        __syncthreads();
        hist[i0] = e0; hist[i1] = e1;
        if (i0 < nkeys) { beg_ui[key_base + i0] = base + e0; end_ui[key_base + i0] = base + e0 + v0; }
        if (i1 < nkeys) { beg_ui[key_base + i1] = base + e1; end_ui[key_base + i1] = base + e1 + v1; }
        __syncthreads();
        for (int i = tid; i < ne; i += 256) {
            unsigned int r = rec[i];
            int slot = atomicAdd(&hist[r >> 18], 1);
            uirec[base + slot] = (int)(r & 0x3FFFFu);
            uval[base + slot] = fval[i];
        }
        return;
    }

    if (bid < KGOFF) {
        // ---------------- user bf16-copy ----------------
        int cid = bid - NB_UI;
        const float4* ue4 = (const float4*)user_emb;
        uint2* a2 = (uint2*)all16;
        int total = N_USERS * 16;
        for (int i = cid * 256 + tid; i < total; i += NCPY * 256) {
            float4 v = ue4[i];
            a2[i] = make_uint2((unsigned)f2bf(v.x) | ((unsigned)f2bf(v.y) << 16),
                               (unsigned)f2bf(v.z) | ((unsigned)f2bf(v.w) << 16));
        }
        return;
    }

    // ---------------- kgagg branch (half-wave, 2 items/wave) ----------------
    int kblk = bid - KGOFF;
    int lane = tid & 63;
    int half = lane >> 5;          // which item of the pair
    int hl   = lane & 31;
    int duo  = hl >> 4;            // edge slot within half
    int ql   = hl & 15;            // dims 4ql..4ql+3
    long wpair = (long)((kblk * 256 + tid) >> 6);
    int it = (int)(wpair * 2 + half);
    if (it >= N_ITEMS) return;
    int w = N_USERS + it;
    // Skip items never read downstream.
    if (!(getbit(colneed, it) | getbit(node_mask, w))) return;

    int ent = i2e[it];
    const uint2* y2 = (const uint2*)y16;
    int degc = ecnt[ent];                    // true kept degree (all edges kept)
    int beg = ent * CAPE;
    int end = beg + min(degc, CAPE);
    float a0 = 0.f, a1 = 0.f, a2 = 0.f, a3 = 0.f;
    float b0 = 0.f, b1 = 0.f, b2 = 0.f, b3 = 0.f;
    int p = beg;
    for (; p + 4 <= end; p += 4) {
        unsigned pk0 = kgslot[p + duo];
        unsigned pk1 = kgslot[p + 2 + duo];
        uint2 v0 = y2[(long)(pk0 & 0x3FFFF) * 16 + ql];
        uint2 v1 = y2[(long)(pk1 & 0x3FFFF) * 16 + ql];
        float4 g0 = gate4[(pk0 >> 18) * 16 + ql];
        float4 g1 = gate4[(pk1 >> 18) * 16 + ql];
        a0 += bf_lo(v0.x) * g0.x;  a1 += bf_hi(v0.x) * g0.y;
        a2 += bf_lo(v0.y) * g0.z;  a3 += bf_hi(v0.y) * g0.w;
        b0 += bf_lo(v1.x) * g1.x;  b1 += bf_hi(v1.x) * g1.y;
        b2 += bf_lo(v1.y) * g1.z;  b3 += bf_hi(v1.y) * g1.w;
    }
    if (p + duo < end) {
        unsigned pk = kgslot[p + duo];
        uint2 v = y2[(long)(pk & 0x3FFFF) * 16 + ql];
        float4 g = gate4[(pk >> 18) * 16 + ql];
        a0 += bf_lo(v.x) * g.x;  a1 += bf_hi(v.x) * g.y;
        a2 += bf_lo(v.y) * g.z;  a3 += bf_hi(v.y) * g.w;
    }
    if (p + 2 + duo < end) {
        unsigned pk = kgslot[p + 2 + duo];
        uint2 v = y2[(long)(pk & 0x3FFFF) * 16 + ql];
        float4 g = gate4[(pk >> 18) * 16 + ql];
        b0 += bf_lo(v.x) * g.x;  b1 += bf_hi(v.x) * g.y;
        b2 += bf_lo(v.y) * g.z;  b3 += bf_hi(v.y) * g.w;
    }
    a0 += b0; a1 += b1; a2 += b2; a3 += b3;
    a0 += __shfl_xor(a0, 16);
    a1 += __shfl_xor(a1, 16);
    a2 += __shfl_xor(a2, 16);
    a3 += __shfl_xor(a3, 16);

    float deg = fmaxf((float)degc, 1.0f);
    float4 xv = ((const float4*)entity_emb)[(long)ent * 16 + ql];
    float v0 = a0 / deg + xv.x;
    float v1 = a1 / deg + xv.y;
    float v2 = a2 / deg + xv.z;
    float v3 = a3 / deg + xv.w;
    v0 = (v0 > 0.0f) ? v0 : (__expf(v0) - 1.0f);
    v1 = (v1 > 0.0f) ? v1 : (__expf(v1) - 1.0f);
    v2 = (v2 > 0.0f) ? v2 : (__expf(v2) - 1.0f);
    v3 = (v3 > 0.0f) ? v3 : (__expf(v3) - 1.0f);
    float ss = v0 * v0 + v1 * v1 + v2 * v2 + v3 * v3;
    ss += __shfl_xor(ss, 1);
    ss += __shfl_xor(ss, 2);
    ss += __shfl_xor(ss, 4);
    ss += __shfl_xor(ss, 8);
    float inv = 1.0f / fmaxf(sqrtf(ss), 1e-12f);
    if (duo == 0) {
        float r0 = v0 * inv, r1 = v1 * inv, r2 = v2 * inv, r3 = v3 * inv;
        if (getbit(node_mask, w))
            ((float4*)all_emb)[(long)w * 16 + ql] = make_float4(r0, r1, r2, r3);
        ((uint2*)all16)[(long)w * 16 + ql] =
            make_uint2((unsigned)f2bf(r0) | ((unsigned)f2bf(r1) << 16),
                       (unsigned)f2bf(r2) | ((unsigned)f2bf(r3) << 16));
    }
}

// ---------------------------------------------------------------------------
// agg_row: aggregate one UI row with the full wave (16 lanes x 4 dims, 4
// edge slots q4).
// ---------------------------------------------------------------------------
__device__ __forceinline__ float4 agg_row(int beg, int end, int q4, int ql,
                                          const int* __restrict__ colrec,
                                          const float* __restrict__ uval,
                                          const uint2* __restrict__ a2p) {
    float a0 = 0.f, a1 = 0.f, a2 = 0.f, a3 = 0.f;
    float b0 = 0.f, b1 = 0.f, b2 = 0.f, b3 = 0.f;
    int p = beg + q4;
    for (; p + 4 < end; p += 8) {          // two independent edge chains
        int   c0 = colrec[p];     float d0 = uval[p];
        int   c1 = colrec[p + 4]; float d1 = uval[p + 4];
        uint2 v0 = a2p[(long)c0 * 16 + ql];
        uint2 v1 = a2p[(long)c1 * 16 + ql];
        a0 += d0 * bf_lo(v0.x);  a1 += d0 * bf_hi(v0.x);
        a2 += d0 * bf_lo(v0.y);  a3 += d0 * bf_hi(v0.y);
        b0 += d1 * bf_lo(v1.x);  b1 += d1 * bf_hi(v1.x);
        b2 += d1 * bf_lo(v1.y);  b3 += d1 * bf_hi(v1.y);
    }
    if (p < end) {
        int c = colrec[p]; float d = uval[p];
        uint2 v = a2p[(long)c * 16 + ql];
        a0 += d * bf_lo(v.x);  a1 += d * bf_hi(v.x);
        a2 += d * bf_lo(v.y);  a3 += d * bf_hi(v.y);
    }
    a0 += b0; a1 += b1; a2 += b2; a3 += b3;
    a0 += __shfl_xor(a0, 16);  a0 += __shfl_xor(a0, 32);
    a1 += __shfl_xor(a1, 16);  a1 += __shfl_xor(a1, 32);
    a2 += __shfl_xor(a2, 16);  a2 += __shfl_xor(a2, 32);
    a3 += __shfl_xor(a3, 16);  a3 += __shfl_xor(a3, 32);
    return make_float4(a0, a1, a2, a3);
}

// ---------------------------------------------------------------------------
// ui_final: ONE WAVE PER SAMPLE — fuses ui_aggregate + final_kernel.
// ---------------------------------------------------------------------------
__global__ __launch_bounds__(256) void ui_final(const int* __restrict__ beg_ui,
                                                const int* __restrict__ end_ui,
                                                const int* __restrict__ colrec,
                                                const float* __restrict__ uval,
                                                const float* __restrict__ all_emb,
                                                const float* __restrict__ user_emb,
                                                const unsigned short* __restrict__ all16,
                                                const int* __restrict__ u,
                                                const int* __restrict__ ipos,
                                                const int* __restrict__ ineg,
                                                const float* __restrict__ rw,
                                                const float* __restrict__ rb,
                                                const float* __restrict__ intentg,
                                                float* __restrict__ out, int B) {
    const uint2* a2p = (const uint2*)all16;
    int lane = threadIdx.x & 63;
    int q4   = lane >> 4;
    int ql   = lane & 15;
    int b = (int)((blockIdx.x * 256 + threadIdx.x) >> 6);
    if (b >= B) return;

    // ---- user row: final_emb value in-register ----
    int ru = u[b];
    float4 s = agg_row(beg_ui[ru], end_ui[ru], q4, ql, colrec, uval, a2p);
    float4 ae = ((const float4*)user_emb)[(long)ru * 16 + ql];
    float up0 = 0.5f * (ae.x + s.x);
    float up1 = 0.5f * (ae.y + s.y);
    float up2 = 0.5f * (ae.z + s.z);
    float up3 = 0.5f * (ae.w + s.w);

    // ---- router + intent ----
    float4 w0 = ((const float4*)rw)[ql];
    float4 w1 = ((const float4*)rw)[16 + ql];
    float l0 = up0 * w0.x + up1 * w0.y + up2 * w0.z + up3 * w0.w;
    float l1 = up0 * w1.x + up1 * w1.y + up2 * w1.z + up3 * w1.w;
    #pragma unroll
    for (int o = 8; o; o >>= 1) {
        l0 += __shfl_xor(l0, o);
        l1 += __shfl_xor(l1, o);
    }
    l0 += rb[0]; l1 += rb[1];
    float m  = fmaxf(l0, l1);
    float e0 = __expf(l0 - m), e1 = __expf(l1 - m);
    float inv = 1.0f / (e0 + e1);
    float p0 = e0 * inv, p1 = e1 * inv;
    float4 it0 = ((const float4*)intentg)[ql];
    float4 it1 = ((const float4*)intentg)[16 + ql];
    float ue0 = up0 + p0 * it0.x + p1 * it1.x;
    float ue1 = up1 + p0 * it0.y + p1 * it1.y;
    float ue2 = up2 + p0 * it0.z + p1 * it1.z;
    float ue3 = up3 + p0 * it0.w + p1 * it1.w;

    // ---- pos item ----
    {
        int ri = N_USERS + ipos[b];
        float4 si = agg_row(beg_ui[ri], end_ui[ri], q4, ql, colrec, uval, a2p);
        float4 ai = ((const float4*)all_emb)[(long)ri * 16 + ql];
        float ie0 = 0.5f * (ai.x + si.x) + ai.x;
        float ie1 = 0.5f * (ai.y + si.y) + ai.y;
        float ie2 = 0.5f * (ai.z + si.z) + ai.z;
        float ie3 = 0.5f * (ai.w + si.w) + ai.w;
        float dp = ue0 * ie0 + ue1 * ie1 + ue2 * ie2 + ue3 * ie3;
        #pragma unroll
        for (int o = 8; o; o >>= 1) dp += __shfl_xor(dp, o);
        if (lane == 0) out[b] = dp;
    }
    // ---- neg item ----
    {
        int ri = N_USERS + ineg[b];
        float4 si = agg_row(beg_ui[ri], end_ui[ri], q4, ql, colrec, uval, a2p);
        float4 ai = ((const float4*)all_emb)[(long)ri * 16 + ql];
        float ie0 = 0.5f * (ai.x + si.x) + ai.x;
        float ie1 = 0.5f * (ai.y + si.y) + ai.y;
        float ie2 = 0.5f * (ai.z + si.z) + ai.z;
        float ie3 = 0.5f * (ai.w + si.w) + ai.w;
        float dp = ue0 * ie0 + ue1 * ie1 + ue2 * ie2 + ue3 * ie3;
        #pragma unroll
        for (int o = 8; o; o >>= 1) dp += __shfl_xor(dp, o);
        if (lane == 0) out[B + b] = dp;
    }
}

extern "C" void kernel_launch(void* const* d_in, const int* in_sizes, int n_in,
                              void* d_out, int out_size, void* d_ws, size_t ws_size,
                              hipStream_t stream) {
    const int*   u          = (const int*)  d_in[0];
    const int*   ipos       = (const int*)  d_in[1];
    const int*   ineg       = (const int*)  d_in[2];
    const float* user_emb   = (const float*)d_in[3];
    const float* entity_emb = (const float*)d_in[4];
    const float* rel_emb    = (const float*)d_in[5];
    const float* iw         = (const float*)d_in[6];
    const float* rw         = (const float*)d_in[7];
    const float* rb         = (const float*)d_in[8];
    const float* kgw        = (const float*)d_in[9];
    const float* ui_vals    = (const float*)d_in[10];
    const int*   i2e        = (const int*)  d_in[11];
    const int*   kg_src     = (const int*)  d_in[12];
    const int*   kg_dst     = (const int*)  d_in[13];
    const int*   kg_rel     = (const int*)  d_in[14];
    const int*   ui_row     = (const int*)  d_in[15];
    const int*   ui_col     = (const int*)  d_in[16];
    float*       out        = (float*)d_out;

    int B    = in_sizes[0];
    int e_kg = in_sizes[12];
    int e_ui = in_sizes[15];

    // ---------------- workspace layout (bytes) ----------------
    // kgslot (200K ents x 48 slots x 4B = 38.4MB) fills the hole left by the
    // deleted final_emb (83.2M..121.6M); ecnt (800KB) sits in the old kgrec
    // region. beg_kg/end_kg/kgrec are gone (no KG sort).
    char* ws = (char*)d_ws;
    unsigned short* y16       = (unsigned short*)(ws + 0);        // 25.6 MB
    float*          all_emb   = (float*)(ws + 25600000);          // 38.4 MB
    unsigned short* all16     = (unsigned short*)(ws + 64000000); // 19.2 MB
    unsigned int*   kgslot    = (unsigned int*)(ws + 83200000);   // 38.4 MB
    int*            ecnt      = (int*)(ws + 121600000);           // 800000 B
    int*            end_ui    = (int*)(ws + 128806144);           // 600000 B
    int*            uirec     = (int*)(ws + 129600000);           // 3.6 MB used
    float*          uval      = (float*)(ws + 133600000);         // 3.6 MB used
    int*            beg_ui    = (int*)(ws + 138400256);           // 600000 B
    unsigned*       ent_mask  = (unsigned*)(ws + 139000512);      // 25088 B (200K bits)
    unsigned*       node_mask = (unsigned*)(ws + 139025600);      // 18752 B (150K bits)
    unsigned*       colneed   = (unsigned*)(ws + 139044352);      // 12544 B (100K bits)
    int*            bcur      = (int*)(ws + 139608704);           // 977 ints
    float2*         gateg     = (float2*)(ws + 139612672);        // 8 KB gate table
    float*          intentg   = (float*)(ws + 139620864);         // 512 B intent table

    hipMemsetAsync(ent_mask, 0, 25088 + 18752 + 12544, stream);  // masks contiguous
    build_masks<<<512, 256, 0, stream>>>(i2e, u, ipos, ineg, rel_emb, iw,
                                         gateg, intentg,
                                         ent_mask, node_mask, bcur, ecnt, B);
    // Fused: scatter [0,768) | matmul [768,2331)
    mm_scatter <<<FUSE_GRID, 512, 0, stream>>>(
        entity_emb, kgw, y16, N_ENT,
        kg_src, kg_dst, kg_rel, ui_row, ui_col, ui_vals,
        ent_mask, node_mask, colneed, bcur, ecnt, kgslot, uirec, uval,
        e_kg, e_ui);
    {   // Fused: finalize_UI [0,586) | user-copy [586,794) | kgagg [794,...)
        int nwaves = N_ITEMS / 2;                  // 50000
        int nkblk  = (nwaves * 64 + 255) / 256;    // 12500
        kgagg_fused<<<KGOFF + nkblk, 256, 0, stream>>>(
            bcur, uirec, uval, beg_ui, end_ui, user_emb,
            ecnt, kgslot, y16, entity_emb, i2e,
            (const float4*)gateg, node_mask, colneed, all_emb, all16);
    }
    {   // one wave per sample: ui aggregation + epilogue fused
        int nblk = (B * 64 + 255) / 256;           // 1024 at B=4096
        ui_final<<<nblk, 256, 0, stream>>>(
            beg_ui, end_ui, uirec, uval, all_emb, user_emb, all16,
            u, ipos, ineg, rw, rb, intentg, out, B);
    }
}

// Round 19
// 265.349 us; speedup vs baseline: 1.1034x; 1.1034x over previous
//
#include <hip/hip_runtime.h>
#include <math.h>

#define N_USERS 50000
#define N_ITEMS 100000
#define N_ENT   200000
#define N_NODES (N_USERS + N_ITEMS)
#define N_REL   32
#define DIM     64

#define NB_KG  391          // KG buckets: dst>>9 (512 keys each)
#define NB_UI  586          // UI buckets: row>>8 (256 keys each)
#define NB_TOT (NB_KG + NB_UI)   // 977
#define CAPK   4096         // fixed capacity per KG bucket (max kept ~2700)
#define CAPU   1536         // fixed capacity per UI bucket (max kept ~850)
#define NMMTILE 1563        // ceil(200000/128) matmul tiles
#define NSCAT  768          // scatter blocks (prefix — measured best, R8)
#define FUSE_GRID (NSCAT + NMMTILE)
#define NCPY   208          // user bf16-copy blocks (fused into kgagg dispatch)
#define KGOFF  (NB_UI + NCPY)    // 794: kgagg role offset in fused dispatch

// R18 NOTE: this is an exact revert to the best-measured config (267.9us,
// R16-output). R17's direct per-entity KG scatter regressed to 292.8us:
// 4B stores into sparse 192B bins doubled WRITE_SIZE (80.9MB) via
// write-allocate line amplification. Dense bucketed kgrec writes + the
// LDS-hist batching are BOTH needed: contention AND coalescing are
// line-granularity effects.

__device__ __forceinline__ unsigned short f2bf(float f) {   // RNE f32->bf16
    unsigned u = __float_as_uint(f);
    u += 0x7FFFu + ((u >> 16) & 1u);
    return (unsigned short)(u >> 16);
}
__device__ __forceinline__ float bf_lo(unsigned v) { return __uint_as_float(v << 16); }
__device__ __forceinline__ float bf_hi(unsigned v) { return __uint_as_float(v & 0xFFFF0000u); }
__device__ __forceinline__ int getbit(const unsigned* m, int i) {
    return (m[i >> 5] >> (i & 31)) & 1;
}

// ---------------------------------------------------------------------------
// build_masks: membership bitmaps + bcur init + gate table + INTENT table.
// ---------------------------------------------------------------------------
__global__ __launch_bounds__(256) void build_masks(const int* __restrict__ i2e,
                                                   const int* __restrict__ u,
                                                   const int* __restrict__ ipos,
                                                   const int* __restrict__ ineg,
                                                   const float* __restrict__ rel_emb,
                                                   const float* __restrict__ iw,
                                                   float2* __restrict__ gateg,
                                                   float* __restrict__ intentg,
                                                   unsigned* __restrict__ ent_mask,
                                                   unsigned* __restrict__ node_mask,
                                                   int* __restrict__ bcur,
                                                   int B) {
    int t = blockIdx.x * 256 + threadIdx.x;
    int stride = gridDim.x * 256;
    for (int i = threadIdx.x; i < NB_TOT; i += 256)          // same-value benign race
        bcur[i] = (i < NB_KG) ? i * CAPK : (i - NB_KG) * CAPU;
    if (blockIdx.x == 0) {
        for (int idx = threadIdx.x; idx < N_REL * 32; idx += 256) {
            int rel = idx >> 5, hl2 = idx & 31;
            float g0 = 1.0f / (1.0f + __expf(-rel_emb[rel * 64 + 2 * hl2]));
            float g1 = 1.0f / (1.0f + __expf(-rel_emb[rel * 64 + 2 * hl2 + 1]));
            gateg[idx] = make_float2(g0, g1);
        }
        if (threadIdx.x < 64) {
            int j = threadIdx.x;
            for (int k = 0; k < 2; k++) {
                float m = -1e30f;
                for (int r = 0; r < N_REL; r++) m = fmaxf(m, iw[k * N_REL + r]);
                float Z = 0.f, acc = 0.f;
                for (int r = 0; r < N_REL; r++) {
                    float e = __expf(iw[k * N_REL + r] - m);
                    Z += e;
                    acc += e * rel_emb[r * 64 + j];
                }
                intentg[k * 64 + j] = acc / Z;
            }
        }
    }
    for (int i = t; i < N_ITEMS; i += stride) {
        int e = i2e[i];
        atomicOr(&ent_mask[e >> 5], 1u << (e & 31));
    }
    for (int i = t; i < 3 * B; i += stride) {
        int r = (i < B) ? u[i]
              : (i < 2 * B) ? N_USERS + ipos[i - B]
                            : N_USERS + ineg[i - 2 * B];
        atomicOr(&node_mask[r >> 5], 1u << (r & 31));
    }
}

// ---------------------------------------------------------------------------
// mm_scatter: FUSED dispatch, TWO roles, PREFIX mapping (measured best):
//   blocks [0, NSCAT)  : edge scatter, 3-PHASE LDS-HIST form (direct-atomic
//     was 6.8x slower: 977 bcur ints = ~61 lines x ~950K cross-XCD atomics)
//   blocks [NSCAT, ...) : ent_matmul tiles (swizzled 48KB LDS)
// Kept UI edges with a USER row mark colneed[col] — the item all16 rows
// ui_final will actually gather.
// Matmul FMA order k-ascending per output -> BIT-IDENTICAL numerics.
// ---------------------------------------------------------------------------
__global__ __launch_bounds__(512) void mm_scatter(const float* __restrict__ x,
                                                  const float* __restrict__ w,
                                                  unsigned short* __restrict__ y16,
                                                  int n_ent,
                                                  const int* __restrict__ kg_src,
                                                  const int* __restrict__ kg_dst,
                                                  const int* __restrict__ kg_rel,
                                                  const int* __restrict__ ui_row,
                                                  const int* __restrict__ ui_col,
                                                  const float* __restrict__ ui_vals,
                                                  const unsigned* __restrict__ ent_mask,
                                                  const unsigned* __restrict__ node_mask,
                                                  unsigned* __restrict__ colneed,
                                                  int* __restrict__ bcur,
                                                  unsigned int* __restrict__ kgrec,
                                                  int* __restrict__ uirec,
                                                  float* __restrict__ uval,
                                                  int e_kg, int e_ui) {
    __shared__ __align__(16) char smem[49152];
    int tid = threadIdx.x;
    int bid = blockIdx.x;

    if (bid < NSCAT) {
        // ---------------- scatter branch (3-phase LDS-hist) ----------------
        int* h     = (int*)smem;
        int* lbase = h + NB_TOT;
        int n = e_kg + e_ui;
        int nchunks = (n + 4095) >> 12;
        for (int c = bid; c < nchunks; c += NSCAT) {
            int base = c << 12;
            for (int i = tid; i < NB_TOT; i += 512) h[i] = 0;
            __syncthreads();
            unsigned int rec[8];
            float val[8];
            int bk[8];
            #pragma unroll
            for (int j = 0; j < 8; j++) {
                int e = base + j * 512 + tid;
                bk[j] = -1;
                if (e < n) {
                    if (e < e_kg) {
                        int d = kg_dst[e];
                        if (getbit(ent_mask, d)) {
                            bk[j]  = d >> 9;
                            rec[j] = (unsigned int)kg_src[e]
                                     | ((unsigned int)kg_rel[e] << 18)
                                     | ((unsigned int)(d & 511) << 23);
                            atomicAdd(&h[bk[j]], 1);
                        }
                    } else {
                        int i2 = e - e_kg;
                        int r  = ui_row[i2];
                        if (getbit(node_mask, r)) {
                            int cc = ui_col[i2];
                            bk[j]  = NB_KG + (r >> 8);
                            rec[j] = (unsigned int)cc
                                     | ((unsigned int)(r & 255) << 18);
                            val[j] = ui_vals[i2];
                            atomicAdd(&h[bk[j]], 1);
                            if (r < N_USERS) {        // user row -> item col needed
                                int ci = cc - N_USERS;
                                atomicOr(&colneed[ci >> 5], 1u << (ci & 31));
                            }
                        }
                    }
                }
            }
            __syncthreads();
            for (int i = tid; i < NB_TOT; i += 512) {
                int cc = h[i];
                lbase[i] = cc ? atomicAdd(&bcur[i], cc) : 0;
            }
            __syncthreads();
            #pragma unroll
            for (int j = 0; j < 8; j++) {
                if (bk[j] >= 0) {
                    int pos = atomicAdd(&lbase[bk[j]], 1);
                    if (bk[j] < NB_KG) {
                        if (pos < (bk[j] + 1) * CAPK) kgrec[pos] = rec[j];
                    } else {
                        int bu = bk[j] - NB_KG;
                        if (pos < (bu + 1) * CAPU) { uirec[pos] = (int)rec[j]; uval[pos] = val[j]; }
                    }
                }
            }
            __syncthreads();
        }
        return;
    }

    // ---------------- matmul branch ----------------
    int mtile = bid - NSCAT;
    float (*xt)[128] = (float (*)[128])smem;            // 32768 B
    float (*wt)[64]  = (float (*)[64])(smem + 32768);   // 16384 B
    int base = mtile * 128;

    #pragma unroll
    for (int q = 0; q < 2; q++) {
        int idx = q * 512 + tid;          // 1024 float4 of w
        int j = idx >> 4, k4 = idx & 15;
        int s0 = (k4 << 2) & 28;          // sigma for rows 4k4..4k4+3
        float4 v = ((const float4*)w)[idx];
        wt[4 * k4 + 0][j ^ s0] = v.x;
        wt[4 * k4 + 1][j ^ s0] = v.y;
        wt[4 * k4 + 2][j ^ s0] = v.z;
        wt[4 * k4 + 3][j ^ s0] = v.w;
    }
    #pragma unroll
    for (int q = 0; q < 4; q++) {
        int idx = q * 512 + tid;          // 2048 float4 of x
        int r = idx >> 4, k4 = idx & 15;
        int gr = base + r;
        int s0 = (k4 << 2) & 28;
        if (gr < n_ent) {
            float4 v = ((const float4*)x)[(long)gr * 16 + k4];
            xt[4 * k4 + 0][r ^ s0] = v.x;
            xt[4 * k4 + 1][r ^ s0] = v.y;
            xt[4 * k4 + 2][r ^ s0] = v.z;
            xt[4 * k4 + 3][r ^ s0] = v.w;
        }
    }
    __syncthreads();

    int j0 = (tid & 7) * 8;               // 8 output cols
    int r0 = (tid >> 3) * 2;              // 2 output rows (0..126)
    float acc[2][8];
    #pragma unroll
    for (int i = 0; i < 2; i++)
        #pragma unroll
        for (int j = 0; j < 8; j++) acc[i][j] = 0.f;

    #pragma unroll 4
    for (int k = 0; k < 64; k++) {
        int s = k & 28;
        float2 xa = *(const float2*)&xt[k][r0 ^ s];
        float4 wa = *(const float4*)&wt[k][j0 ^ s];
        float4 wb = *(const float4*)&wt[k][(j0 + 4) ^ s];
        float xr[2] = {xa.x, xa.y};
        float wr[8] = {wa.x, wa.y, wa.z, wa.w, wb.x, wb.y, wb.z, wb.w};
        #pragma unroll
        for (int i = 0; i < 2; i++)
            #pragma unroll
            for (int j = 0; j < 8; j++)
                acc[i][j] += xr[i] * wr[j];
    }

    #pragma unroll
    for (int i = 0; i < 2; i++) {
        int gr = base + r0 + i;
        if (gr < n_ent) {
            uint4 o;
            o.x = (unsigned)f2bf(acc[i][0]) | ((unsigned)f2bf(acc[i][1]) << 16);
            o.y = (unsigned)f2bf(acc[i][2]) | ((unsigned)f2bf(acc[i][3]) << 16);
            o.z = (unsigned)f2bf(acc[i][4]) | ((unsigned)f2bf(acc[i][5]) << 16);
            o.w = (unsigned)f2bf(acc[i][6]) | ((unsigned)f2bf(acc[i][7]) << 16);
            *(uint4*)&y16[(long)gr * 64 + j0] = o;
        }
    }
}

// ---------------------------------------------------------------------------
// finalize_kg: KG buckets ONLY (391 blocks) — the sole dependency of kgagg.
// ---------------------------------------------------------------------------
__global__ __launch_bounds__(256) void finalize_kg(const int* __restrict__ bcur,
                                                   unsigned int* __restrict__ kgrec,
                                                   int* __restrict__ beg_kg,
                                                   int* __restrict__ end_kg) {
    __shared__ unsigned int rec[CAPK];
    __shared__ int hist[512];
    int b    = blockIdx.x;
    int base = b * CAPK;
    int ne   = min(bcur[b] - base, CAPK);
    int key_base = b << 9;
    int nkeys = min(512, N_ENT - key_base);
    int tid = threadIdx.x;

    for (int i = tid; i < ne; i += 256) rec[i] = kgrec[base + i];
    for (int i = tid; i < 512; i += 256) hist[i] = 0;
    __syncthreads();
    for (int i = tid; i < ne; i += 256)
        atomicAdd(&hist[rec[i] >> 23], 1);
    __syncthreads();
    int i0 = tid, i1 = tid + 256;
    int v0 = hist[i0], v1 = hist[i1];
    __syncthreads();
    for (int o = 1; o < 512; o <<= 1) {
        int a0 = (i0 >= o) ? hist[i0 - o] : 0;
        int a1 = (i1 >= o) ? hist[i1 - o] : 0;
        __syncthreads();
        hist[i0] += a0; hist[i1] += a1;
        __syncthreads();
    }
    int e0 = hist[i0] - v0, e1 = hist[i1] - v1;
    __syncthreads();
    hist[i0] = e0; hist[i1] = e1;
    if (i0 < nkeys) { beg_kg[key_base + i0] = base + e0; end_kg[key_base + i0] = base + e0 + v0; }
    if (i1 < nkeys) { beg_kg[key_base + i1] = base + e1; end_kg[key_base + i1] = base + e1 + v1; }
    __syncthreads();
    for (int i = tid; i < ne; i += 256) {
        unsigned int r = rec[i];
        int slot = atomicAdd(&hist[r >> 23], 1);
        kgrec[base + slot] = r & 0x7FFFFFu;
    }
}

// ---------------------------------------------------------------------------
// kgagg_fused: THREE roles — finalize_UI [0,586) | user-copy [586,794) |
// kgagg items [794,...) (half-wave, 2 items/wave, measured best).
// kgagg halves whose item is neither colneed nor node_mask exit before the
// gather — ~half the items are never read downstream.
// ---------------------------------------------------------------------------
__global__ __launch_bounds__(256) void kgagg_fused(const int* __restrict__ bcur,
                                                   int* __restrict__ uirec,
                                                   float* __restrict__ uval,
                                                   int* __restrict__ beg_ui,
                                                   int* __restrict__ end_ui,
                                                   const float* __restrict__ user_emb,
                                                   const int* __restrict__ beg_kg,
                                                   const int* __restrict__ end_kg,
                                                   const unsigned int* __restrict__ packed,
                                                   const unsigned short* __restrict__ y16,
                                                   const float* __restrict__ entity_emb,
                                                   const int* __restrict__ i2e,
                                                   const float4* __restrict__ gate4,
                                                   const unsigned* __restrict__ node_mask,
                                                   const unsigned* __restrict__ colneed,
                                                   float* __restrict__ all_emb,
                                                   unsigned short* __restrict__ all16) {
    __shared__ __align__(16) char smem[14336];   // rec_ui[1536] + fval[1536] + hist[512]
    int tid = threadIdx.x;
    int bid = blockIdx.x;

    if (bid < NB_UI) {
        // ---------------- finalize UI bucket ----------------
        unsigned int* rec = (unsigned int*)smem;            // 6144 B
        float* fval = (float*)(smem + 6144);                // 6144 B
        int*   hist = (int*)(smem + 12288);                 // 2048 B
        int b    = bid;
        int base = b * CAPU;
        int ne   = min(bcur[NB_KG + b] - base, CAPU);
        int key_base = b << 8;
        int nkeys = min(256, N_NODES - key_base);

        for (int i = tid; i < ne; i += 256) {
            rec[i] = (unsigned int)uirec[base + i];
            fval[i] = uval[base + i];
        }
        for (int i = tid; i < 512; i += 256) hist[i] = 0;
        __syncthreads();
        for (int i = tid; i < ne; i += 256)
            atomicAdd(&hist[rec[i] >> 18], 1);
        __syncthreads();
        int i0 = tid, i1 = tid + 256;
        int v0 = hist[i0], v1 = hist[i1];
        __syncthreads();
        for (int o = 1; o < 512; o <<= 1) {
            int a0 = (i0 >= o) ? hist[i0 - o] : 0;
            int a1 = (i1 >= o) ? hist[i1 - o] : 0;
            __syncthreads();
            hist[i0] += a0; hist[i1] += a1;
            __syncthreads();
        }
        int e0 = hist[i0] - v0, e1 = hist[i1] - v1;
        __syncthreads();
        hist[i0] = e0; hist[i1] = e1;
        if (i0 < nkeys) { beg_ui[key_base + i0] = base + e0; end_ui[key_base + i0] = base + e0 + v0; }
        if (i1 < nkeys) { beg_ui[key_base + i1] = base + e1; end_ui[key_base + i1] = base + e1 + v1; }
        __syncthreads();
        for (int i = tid; i < ne; i += 256) {
            unsigned int r = rec[i];
            int slot = atomicAdd(&hist[r >> 18], 1);
            uirec[base + slot] = (int)(r & 0x3FFFFu);
            uval[base + slot] = fval[i];
        }
        return;
    }

    if (bid < KGOFF) {
        // ---------------- user bf16-copy ----------------
        int cid = bid - NB_UI;
        const float4* ue4 = (const float4*)user_emb;
        uint2* a2 = (uint2*)all16;
        int total = N_USERS * 16;
        for (int i = cid * 256 + tid; i < total; i += NCPY * 256) {
            float4 v = ue4[i];
            a2[i] = make_uint2((unsigned)f2bf(v.x) | ((unsigned)f2bf(v.y) << 16),
                               (unsigned)f2bf(v.z) | ((unsigned)f2bf(v.w) << 16));
        }
        return;
    }

    // ---------------- kgagg branch (half-wave, 2 items/wave) ----------------
    int kblk = bid - KGOFF;
    int lane = tid & 63;
    int half = lane >> 5;          // which item of the pair
    int hl   = lane & 31;
    int duo  = hl >> 4;            // edge slot within half
    int ql   = hl & 15;            // dims 4ql..4ql+3
    long wpair = (long)((kblk * 256 + tid) >> 6);
    int it = (int)(wpair * 2 + half);
    if (it >= N_ITEMS) return;
    int w = N_USERS + it;
    // Skip items never read downstream.
    if (!(getbit(colneed, it) | getbit(node_mask, w))) return;

    int ent = i2e[it];
    const uint2* y2 = (const uint2*)y16;
    int beg = beg_kg[ent], end = end_kg[ent];
    float a0 = 0.f, a1 = 0.f, a2 = 0.f, a3 = 0.f;
    float b0 = 0.f, b1 = 0.f, b2 = 0.f, b3 = 0.f;
    int p = beg;
    for (; p + 4 <= end; p += 4) {
        unsigned pk0 = packed[p + duo];
        unsigned pk1 = packed[p + 2 + duo];
        uint2 v0 = y2[(long)(pk0 & 0x3FFFF) * 16 + ql];
        uint2 v1 = y2[(long)(pk1 & 0x3FFFF) * 16 + ql];
        float4 g0 = gate4[(pk0 >> 18) * 16 + ql];
        float4 g1 = gate4[(pk1 >> 18) * 16 + ql];
        a0 += bf_lo(v0.x) * g0.x;  a1 += bf_hi(v0.x) * g0.y;
        a2 += bf_lo(v0.y) * g0.z;  a3 += bf_hi(v0.y) * g0.w;
        b0 += bf_lo(v1.x) * g1.x;  b1 += bf_hi(v1.x) * g1.y;
        b2 += bf_lo(v1.y) * g1.z;  b3 += bf_hi(v1.y) * g1.w;
    }
    if (p + duo < end) {
        unsigned pk = packed[p + duo];
        uint2 v = y2[(long)(pk & 0x3FFFF) * 16 + ql];
        float4 g = gate4[(pk >> 18) * 16 + ql];
        a0 += bf_lo(v.x) * g.x;  a1 += bf_hi(v.x) * g.y;
        a2 += bf_lo(v.y) * g.z;  a3 += bf_hi(v.y) * g.w;
    }
    if (p + 2 + duo < end) {
        unsigned pk = packed[p + 2 + duo];
        uint2 v = y2[(long)(pk & 0x3FFFF) * 16 + ql];
        float4 g = gate4[(pk >> 18) * 16 + ql];
        b0 += bf_lo(v.x) * g.x;  b1 += bf_hi(v.x) * g.y;
        b2 += bf_lo(v.y) * g.z;  b3 += bf_hi(v.y) * g.w;
    }
    a0 += b0; a1 += b1; a2 += b2; a3 += b3;
    a0 += __shfl_xor(a0, 16);
    a1 += __shfl_xor(a1, 16);
    a2 += __shfl_xor(a2, 16);
    a3 += __shfl_xor(a3, 16);

    float deg = fmaxf((float)(end - beg), 1.0f);
    float4 xv = ((const float4*)entity_emb)[(long)ent * 16 + ql];
    float v0 = a0 / deg + xv.x;
    float v1 = a1 / deg + xv.y;
    float v2 = a2 / deg + xv.z;
    float v3 = a3 / deg + xv.w;
    v0 = (v0 > 0.0f) ? v0 : (__expf(v0) - 1.0f);
    v1 = (v1 > 0.0f) ? v1 : (__expf(v1) - 1.0f);
    v2 = (v2 > 0.0f) ? v2 : (__expf(v2) - 1.0f);
    v3 = (v3 > 0.0f) ? v3 : (__expf(v3) - 1.0f);
    float ss = v0 * v0 + v1 * v1 + v2 * v2 + v3 * v3;
    ss += __shfl_xor(ss, 1);
    ss += __shfl_xor(ss, 2);
    ss += __shfl_xor(ss, 4);
    ss += __shfl_xor(ss, 8);
    float inv = 1.0f / fmaxf(sqrtf(ss), 1e-12f);
    if (duo == 0) {
        float r0 = v0 * inv, r1 = v1 * inv, r2 = v2 * inv, r3 = v3 * inv;
        if (getbit(node_mask, w))
            ((float4*)all_emb)[(long)w * 16 + ql] = make_float4(r0, r1, r2, r3);
        ((uint2*)all16)[(long)w * 16 + ql] =
            make_uint2((unsigned)f2bf(r0) | ((unsigned)f2bf(r1) << 16),
                       (unsigned)f2bf(r2) | ((unsigned)f2bf(r3) << 16));
    }
}

// ---------------------------------------------------------------------------
// agg_row: aggregate one UI row with the full wave (16 lanes x 4 dims, 4
// edge slots q4).
// ---------------------------------------------------------------------------
__device__ __forceinline__ float4 agg_row(int beg, int end, int q4, int ql,
                                          const int* __restrict__ colrec,
                                          const float* __restrict__ uval,
                                          const uint2* __restrict__ a2p) {
    float a0 = 0.f, a1 = 0.f, a2 = 0.f, a3 = 0.f;
    float b0 = 0.f, b1 = 0.f, b2 = 0.f, b3 = 0.f;
    int p = beg + q4;
    for (; p + 4 < end; p += 8) {          // two independent edge chains
        int   c0 = colrec[p];     float d0 = uval[p];
        int   c1 = colrec[p + 4]; float d1 = uval[p + 4];
        uint2 v0 = a2p[(long)c0 * 16 + ql];
        uint2 v1 = a2p[(long)c1 * 16 + ql];
        a0 += d0 * bf_lo(v0.x);  a1 += d0 * bf_hi(v0.x);
        a2 += d0 * bf_lo(v0.y);  a3 += d0 * bf_hi(v0.y);
        b0 += d1 * bf_lo(v1.x);  b1 += d1 * bf_hi(v1.x);
        b2 += d1 * bf_lo(v1.y);  b3 += d1 * bf_hi(v1.y);
    }
    if (p < end) {
        int c = colrec[p]; float d = uval[p];
        uint2 v = a2p[(long)c * 16 + ql];
        a0 += d * bf_lo(v.x);  a1 += d * bf_hi(v.x);
        a2 += d * bf_lo(v.y);  a3 += d * bf_hi(v.y);
    }
    a0 += b0; a1 += b1; a2 += b2; a3 += b3;
    a0 += __shfl_xor(a0, 16);  a0 += __shfl_xor(a0, 32);
    a1 += __shfl_xor(a1, 16);  a1 += __shfl_xor(a1, 32);
    a2 += __shfl_xor(a2, 16);  a2 += __shfl_xor(a2, 32);
    a3 += __shfl_xor(a3, 16);  a3 += __shfl_xor(a3, 32);
    return make_float4(a0, a1, a2, a3);
}

// ---------------------------------------------------------------------------
// ui_final: ONE WAVE PER SAMPLE — fuses ui_aggregate + final_kernel.
// ---------------------------------------------------------------------------
__global__ __launch_bounds__(256) void ui_final(const int* __restrict__ beg_ui,
                                                const int* __restrict__ end_ui,
                                                const int* __restrict__ colrec,
                                                const float* __restrict__ uval,
                                                const float* __restrict__ all_emb,
                                                const float* __restrict__ user_emb,
                                                const unsigned short* __restrict__ all16,
                                                const int* __restrict__ u,
                                                const int* __restrict__ ipos,
                                                const int* __restrict__ ineg,
                                                const float* __restrict__ rw,
                                                const float* __restrict__ rb,
                                                const float* __restrict__ intentg,
                                                float* __restrict__ out, int B) {
    const uint2* a2p = (const uint2*)all16;
    int lane = threadIdx.x & 63;
    int q4   = lane >> 4;
    int ql   = lane & 15;
    int b = (int)((blockIdx.x * 256 + threadIdx.x) >> 6);
    if (b >= B) return;

    // ---- user row: final_emb value in-register ----
    int ru = u[b];
    float4 s = agg_row(beg_ui[ru], end_ui[ru], q4, ql, colrec, uval, a2p);
    float4 ae = ((const float4*)user_emb)[(long)ru * 16 + ql];
    float up0 = 0.5f * (ae.x + s.x);
    float up1 = 0.5f * (ae.y + s.y);
    float up2 = 0.5f * (ae.z + s.z);
    float up3 = 0.5f * (ae.w + s.w);

    // ---- router + intent ----
    float4 w0 = ((const float4*)rw)[ql];
    float4 w1 = ((const float4*)rw)[16 + ql];
    float l0 = up0 * w0.x + up1 * w0.y + up2 * w0.z + up3 * w0.w;
    float l1 = up0 * w1.x + up1 * w1.y + up2 * w1.z + up3 * w1.w;
    #pragma unroll
    for (int o = 8; o; o >>= 1) {
        l0 += __shfl_xor(l0, o);
        l1 += __shfl_xor(l1, o);
    }
    l0 += rb[0]; l1 += rb[1];
    float m  = fmaxf(l0, l1);
    float e0 = __expf(l0 - m), e1 = __expf(l1 - m);
    float inv = 1.0f / (e0 + e1);
    float p0 = e0 * inv, p1 = e1 * inv;
    float4 it0 = ((const float4*)intentg)[ql];
    float4 it1 = ((const float4*)intentg)[16 + ql];
    float ue0 = up0 + p0 * it0.x + p1 * it1.x;
    float ue1 = up1 + p0 * it0.y + p1 * it1.y;
    float ue2 = up2 + p0 * it0.z + p1 * it1.z;
    float ue3 = up3 + p0 * it0.w + p1 * it1.w;

    // ---- pos item ----
    {
        int ri = N_USERS + ipos[b];
        float4 si = agg_row(beg_ui[ri], end_ui[ri], q4, ql, colrec, uval, a2p);
        float4 ai = ((const float4*)all_emb)[(long)ri * 16 + ql];
        float ie0 = 0.5f * (ai.x + si.x) + ai.x;
        float ie1 = 0.5f * (ai.y + si.y) + ai.y;
        float ie2 = 0.5f * (ai.z + si.z) + ai.z;
        float ie3 = 0.5f * (ai.w + si.w) + ai.w;
        float dp = ue0 * ie0 + ue1 * ie1 + ue2 * ie2 + ue3 * ie3;
        #pragma unroll
        for (int o = 8; o; o >>= 1) dp += __shfl_xor(dp, o);
        if (lane == 0) out[b] = dp;
    }
    // ---- neg item ----
    {
        int ri = N_USERS + ineg[b];
        float4 si = agg_row(beg_ui[ri], end_ui[ri], q4, ql, colrec, uval, a2p);
        float4 ai = ((const float4*)all_emb)[(long)ri * 16 + ql];
        float ie0 = 0.5f * (ai.x + si.x) + ai.x;
        float ie1 = 0.5f * (ai.y + si.y) + ai.y;
        float ie2 = 0.5f * (ai.z + si.z) + ai.z;
        float ie3 = 0.5f * (ai.w + si.w) + ai.w;
        float dp = ue0 * ie0 + ue1 * ie1 + ue2 * ie2 + ue3 * ie3;
        #pragma unroll
        for (int o = 8; o; o >>= 1) dp += __shfl_xor(dp, o);
        if (lane == 0) out[B + b] = dp;
    }
}

extern "C" void kernel_launch(void* const* d_in, const int* in_sizes, int n_in,
                              void* d_out, int out_size, void* d_ws, size_t ws_size,
                              hipStream_t stream) {
    const int*   u          = (const int*)  d_in[0];
    const int*   ipos       = (const int*)  d_in[1];
    const int*   ineg       = (const int*)  d_in[2];
    const float* user_emb   = (const float*)d_in[3];
    const float* entity_emb = (const float*)d_in[4];
    const float* rel_emb    = (const float*)d_in[5];
    const float* iw         = (const float*)d_in[6];
    const float* rw         = (const float*)d_in[7];
    const float* rb         = (const float*)d_in[8];
    const float* kgw        = (const float*)d_in[9];
    const float* ui_vals    = (const float*)d_in[10];
    const int*   i2e        = (const int*)  d_in[11];
    const int*   kg_src     = (const int*)  d_in[12];
    const int*   kg_dst     = (const int*)  d_in[13];
    const int*   kg_rel     = (const int*)  d_in[14];
    const int*   ui_row     = (const int*)  d_in[15];
    const int*   ui_col     = (const int*)  d_in[16];
    float*       out        = (float*)d_out;

    int B    = in_sizes[0];
    int e_kg = in_sizes[12];
    int e_ui = in_sizes[15];

    // ---------------- workspace layout (bytes) ----------------
    char* ws = (char*)d_ws;
    unsigned short* y16       = (unsigned short*)(ws + 0);        // 25.6 MB
    float*          all_emb   = (float*)(ws + 25600000);          // 38.4 MB
    unsigned short* all16     = (unsigned short*)(ws + 64000000); // 19.2 MB
    unsigned int*   kgrec     = (unsigned int*)(ws + 121600000);  // 6.4 MB used
    int*            end_kg    = (int*)(ws + 128006144);           // 800000 B
    int*            end_ui    = (int*)(ws + 128806144);           // 600000 B
    int*            uirec     = (int*)(ws + 129600000);           // 3.6 MB used
    float*          uval      = (float*)(ws + 133600000);         // 3.6 MB used
    int*            beg_kg    = (int*)(ws + 137600000);           // 800000 B
    int*            beg_ui    = (int*)(ws + 138400256);           // 600000 B
    unsigned*       ent_mask  = (unsigned*)(ws + 139000512);      // 25088 B (200K bits)
    unsigned*       node_mask = (unsigned*)(ws + 139025600);      // 18752 B (150K bits)
    unsigned*       colneed   = (unsigned*)(ws + 139044352);      // 12544 B (100K bits)
    int*            bcur      = (int*)(ws + 139608704);           // 977 ints
    float2*         gateg     = (float2*)(ws + 139612672);        // 8 KB gate table
    float*          intentg   = (float*)(ws + 139620864);         // 512 B intent table

    hipMemsetAsync(ent_mask, 0, 25088 + 18752 + 12544, stream);  // masks contiguous
    build_masks<<<512, 256, 0, stream>>>(i2e, u, ipos, ineg, rel_emb, iw,
                                         gateg, intentg,
                                         ent_mask, node_mask, bcur, B);
    // Fused: scatter [0,768) | matmul [768,2331)
    mm_scatter <<<FUSE_GRID, 512, 0, stream>>>(
        entity_emb, kgw, y16, N_ENT,
        kg_src, kg_dst, kg_rel, ui_row, ui_col, ui_vals,
        ent_mask, node_mask, colneed, bcur, kgrec, uirec, uval, e_kg, e_ui);
    // KG buckets only — the sole dependency of kgagg
    finalize_kg<<<NB_KG, 256, 0, stream>>>(bcur, kgrec, beg_kg, end_kg);
    {   // Fused: finalize_UI [0,586) | user-copy [586,794) | kgagg [794,...)
        int nwaves = N_ITEMS / 2;                  // 50000
        int nkblk  = (nwaves * 64 + 255) / 256;    // 12500
        kgagg_fused<<<KGOFF + nkblk, 256, 0, stream>>>(
            bcur, uirec, uval, beg_ui, end_ui, user_emb,
            beg_kg, end_kg, kgrec, y16, entity_emb, i2e,
            (const float4*)gateg, node_mask, colneed, all_emb, all16);
    }
    {   // one wave per sample: ui aggregation + epilogue fused
        int nblk = (B * 64 + 255) / 256;           // 1024 at B=4096
        ui_final<<<nblk, 256, 0, stream>>>(
            beg_ui, end_ui, uirec, uval, all_emb, user_emb, all16,
            u, ipos, ineg, rw, rb, intentg, out, B);
    }
}